// Round 6
// baseline (193.613 us; speedup 1.0000x reference)
//
#include <hip/hip_runtime.h>
#include <math.h>

#define BH   32
#define NSEQ 2048
#define DH   64
#define NH   16
#define LOG2E 1.44269504088896f

typedef _Float16 f16x8 __attribute__((ext_vector_type(8)));
typedef __fp16   fp16x2 __attribute__((ext_vector_type(2)));
typedef float    f32x16v __attribute__((ext_vector_type(16)));

#if __has_builtin(__builtin_amdgcn_exp2f)
#define EXP2F(x) __builtin_amdgcn_exp2f(x)
#else
#define EXP2F(x) exp2f(x)
#endif

static __device__ __forceinline__ unsigned packh_rne(float a, float b) {
    union { _Float16 h[2]; unsigned u; } x;
    x.h[0] = (_Float16)a; x.h[1] = (_Float16)b;
    return x.u;
}
static __device__ __forceinline__ unsigned pkrtz(float a, float b) {
    fp16x2 r = __builtin_amdgcn_cvt_pkrtz(a, b);
    return __builtin_bit_cast(unsigned, r);
}
#if __has_builtin(__builtin_amdgcn_perm)
#define PERM(a, b, s) __builtin_amdgcn_perm((a), (b), (s))
#else
static __device__ __forceinline__ unsigned PERM(unsigned a, unsigned b, unsigned s) {
    if (s == 0x05040100u) return (b & 0xffffu) | (a << 16);
    return (b >> 16) | (a & 0xffff0000u);
}
#endif

// ---------------- fused prep: q-norm/rope, k-norm/rope, v-pack ---------------
// grid.x: [0,8192) q rows, [8192,16384) k rows, [16384,17408) v tiles.
__global__ __launch_bounds__(256) void prep_all(
    const float* __restrict__ q, const float* __restrict__ k, const float* __restrict__ v,
    const float* __restrict__ qs, const float* __restrict__ ksc,
    unsigned* __restrict__ qh, unsigned* __restrict__ kh, unsigned* __restrict__ vt2) {
    const int bid = blockIdx.x;
    const int t = threadIdx.x;
    if (bid < 16384) {
        const bool isq = bid < 8192;
        const float* in = isq ? q : k;
        const float* sc = isq ? qs : ksc;
        unsigned* outp  = isq ? qh : kh;
        const float smul = isq ? 0.125f * LOG2E : 1.0f;
        const int sb = bid & 8191;
        __shared__ float2 tab[8][32];
        {
            int pr = t >> 5, p = t & 31;
            int pos = (sb * 8 + pr) & (NSEQ - 1);
            float infr = exp2f(-(float)p * (13.287712379549449f / 32.0f));
            float sn, cs;
            sincosf((float)pos * infr, &sn, &cs);
            tab[pr][p] = make_float2(cs, sn);
        }
        __syncthreads();
        const int w = t >> 6, lane = t & 63;
        const int c = lane & 31, hfr = lane >> 5;
        const int rl = w * 2 + hfr;
        const int row = sb * 8 + rl;
        float2 x2 = *(const float2*)(in + (size_t)row * DH + 2 * c);
        float ss = x2.x * x2.x + x2.y * x2.y;
        #pragma unroll
        for (int off = 16; off > 0; off >>= 1) ss += __shfl_xor(ss, off);
        float inv = 1.0f / fmaxf(sqrtf(ss), 1e-12f);
        float2 s2 = *(const float2*)(sc + 2 * c);
        float t0 = x2.x * inv * s2.x;
        float t1 = x2.y * inv * s2.y;
        float p0 = __shfl_xor(t0, 16);
        float p1 = __shfl_xor(t1, 16);
        float r0 = (c < 16) ? -p0 : p0;
        float r1 = (c < 16) ? -p1 : p1;
        float4 cc = *(const float4*)&tab[rl][(2 * c) & 31];
        float o0 = (t0 * cc.x + r0 * cc.y) * smul;
        float o1 = (t1 * cc.z + r1 * cc.w) * smul;
        outp[row * 32 + c] = packh_rne(o0, o1);
    } else {
        // V: fp32 [bh][key][dim] -> u32 pairs [bh][dp=32][key], LDS bounce so
        // global reads AND writes are contiguous uint4.
        const int sb = bid - 16384;
        const int kt = sb & 31, bh = sb >> 5;
        __shared__ float Lv[64 * 68];
        #pragma unroll
        for (int i = 0; i < 4; ++i) {
            int chunk = t + 256 * i;
            int r = chunk >> 4, fg = chunk & 15;
            *(float4*)&Lv[r * 68 + fg * 4] =
                *(const float4*)(v + ((size_t)bh * NSEQ + kt * 64 + r) * DH + fg * 4);
        }
        __syncthreads();
        const int dp = t >> 3, kg = t & 7;
        unsigned u[8];
        #pragma unroll
        for (int j = 0; j < 8; ++j) {
            int key = kg * 8 + j;
            float2 f2 = *(const float2*)&Lv[key * 68 + 2 * dp];
            u[j] = pkrtz(f2.x, f2.y);
        }
        unsigned* dst = vt2 + ((size_t)bh * 32 + dp) * NSEQ + kt * 64 + kg * 8;
        *(uint4*)(dst + 0) = make_uint4(u[0], u[1], u[2], u[3]);
        *(uint4*)(dst + 4) = make_uint4(u[4], u[5], u[6], u[7]);
    }
}

// ---------------- flash attention: 4-wave WG, in-WG split-K/2 ----------------
// WG 256 = 4 waves: wave w -> (kv = w>>1 key half, wq = w&1 q-subtile of 32 rows).
// 64 q-rows/WG -> grid 1024 WGs (4 WGs/CU, 4 waves/SIMD). 64-key tiles, 16 iters,
// single-buffered LDS (36 KB) + register prefetch. Fixed-max softmax; partials
// combine by plain sums via LDS epilogue (aliases K/V LDS).
__global__ __launch_bounds__(256, 4) void attn_kernel(
    const unsigned* __restrict__ qh, const unsigned* __restrict__ khg,
    const unsigned* __restrict__ vt2, float* __restrict__ out) {

    __shared__ __align__(16) unsigned char SMEM[36864];
    // Ks half h: SMEM + h*9216 (64 rows x 72 halfs); Vs half h: SMEM + 18432 + h*9216

    const int bh = blockIdx.y, qb = blockIdx.x;
    const int tid = threadIdx.x;
    const int w = tid >> 6, kv = w >> 1, wq = w & 1;
    const int lane = tid & 63;
    const int c = lane & 31, hf = lane >> 5;

    const _Float16* qbase = (const _Float16*)qh + ((size_t)bh * NSEQ + qb * 64) * DH;
    const _Float16* kbase = (const _Float16*)khg + (size_t)bh * NSEQ * DH;
    const unsigned* vbase = vt2 + (size_t)bh * 32 * NSEQ;

    // staging roles: threads 0-127 stage half 0, 128-255 half 1
    const int sh = tid >> 7, st = tid & 127;
    const _Float16* kS = kbase + (size_t)sh * 1024 * DH;
    const unsigned* vS = vbase + sh * 1024;
    _Float16* KsW = (_Float16*)(SMEM + sh * 9216);
    _Float16* VsW = (_Float16*)(SMEM + 18432 + sh * 9216);
    // compute-side pointers (wave's key half)
    const _Float16* KsR = (const _Float16*)(SMEM + kv * 9216);
    const _Float16* VsR = (const _Float16*)(SMEM + 18432 + kv * 9216);

    // Q frags from global: B[k=dim][n=qrow]
    f16x8 qf[4];
    #pragma unroll
    for (int ks = 0; ks < 4; ++ks)
        qf[ks] = *(const f16x8*)(qbase + (wq * 32 + c) * DH + ks * 16 + hf * 8);

    // stage tile 0
    #pragma unroll
    for (int i = 0; i < 4; ++i) {
        int chunk = st + 128 * i;
        int r = chunk >> 3, sg = chunk & 7;
        *(uint4*)&KsW[r * 72 + sg * 8] = *(const uint4*)(kS + r * DH + sg * 8);
    }
    #pragma unroll
    for (int i = 0; i < 4; ++i) {
        int chunk = st + 128 * i;
        int dp = chunk >> 4, kq = (chunk & 15) * 4;
        uint4 vr = *(const uint4*)(vS + (size_t)dp * NSEQ + kq);
        uint2 lo, hi;
        lo.x = PERM(vr.y, vr.x, 0x05040100u); hi.x = PERM(vr.y, vr.x, 0x07060302u);
        lo.y = PERM(vr.w, vr.z, 0x05040100u); hi.y = PERM(vr.w, vr.z, 0x07060302u);
        *(uint2*)&VsW[(2 * dp) * 72 + kq]     = lo;
        *(uint2*)&VsW[(2 * dp + 1) * 72 + kq] = hi;
    }

    f32x16v o[2];
    #pragma unroll
    for (int mt = 0; mt < 2; ++mt)
        #pragma unroll
        for (int r = 0; r < 16; ++r) o[mt][r] = 0.f;
    float lpart = 0.f;

    __syncthreads();

    for (int jt = 0; jt < 16; ++jt) {
        uint4 kpre[4], vpre[4];
        if (jt + 1 < 16) {
            #pragma unroll
            for (int i = 0; i < 4; ++i) {
                int chunk = st + 128 * i;
                int r = chunk >> 3, sg = chunk & 7;
                kpre[i] = *(const uint4*)(kS + (size_t)(jt + 1) * 64 * DH + r * DH + sg * 8);
            }
            #pragma unroll
            for (int i = 0; i < 4; ++i) {
                int chunk = st + 128 * i;
                int dp = chunk >> 4, kq = (chunk & 15) * 4;
                vpre[i] = *(const uint4*)(vS + (size_t)dp * NSEQ + (jt + 1) * 64 + kq);
            }
        }

        // S^T = K * Q^T : s[mt] = keys mt*32.., qrow = c, key = (r&3)+8*(r>>2)+4*hf
        f32x16v s[2];
        #pragma unroll
        for (int mt = 0; mt < 2; ++mt)
            #pragma unroll
            for (int r = 0; r < 16; ++r) s[mt][r] = 0.f;
        #pragma unroll
        for (int ks = 0; ks < 4; ++ks) {
            f16x8 ka0 = *(const f16x8*)&KsR[c * 72 + ks * 16 + hf * 8];
            f16x8 ka1 = *(const f16x8*)&KsR[(32 + c) * 72 + ks * 16 + hf * 8];
            s[0] = __builtin_amdgcn_mfma_f32_32x32x16_f16(ka0, qf[ks], s[0], 0, 0, 0);
            s[1] = __builtin_amdgcn_mfma_f32_32x32x16_f16(ka1, qf[ks], s[1], 0, 0, 0);
        }

        // exp2 (fixed max) + running denominator
        #pragma unroll
        for (int mt = 0; mt < 2; ++mt)
            #pragma unroll
            for (int r = 0; r < 16; ++r) {
                float pv = EXP2F(s[mt][r]);
                s[mt][r] = pv;
                lpart += pv;
            }

        // O^T += V^T * P^T ; B-frags built in-register from C-layout
        #pragma unroll
        for (int mt = 0; mt < 2; ++mt) {
            #pragma unroll
            for (int kk = 0; kk < 2; ++kk) {
                unsigned P01 = pkrtz(s[mt][kk * 8 + 0], s[mt][kk * 8 + 1]);
                unsigned P23 = pkrtz(s[mt][kk * 8 + 2], s[mt][kk * 8 + 3]);
                unsigned P45 = pkrtz(s[mt][kk * 8 + 4], s[mt][kk * 8 + 5]);
                unsigned P67 = pkrtz(s[mt][kk * 8 + 6], s[mt][kk * 8 + 7]);
                unsigned x01 = (unsigned)__shfl_xor((int)P01, 32);
                unsigned x23 = (unsigned)__shfl_xor((int)P23, 32);
                unsigned x45 = (unsigned)__shfl_xor((int)P45, 32);
                unsigned x67 = (unsigned)__shfl_xor((int)P67, 32);
                union { unsigned u[4]; f16x8 v; } B;
                B.u[0] = hf ? x45 : P01;
                B.u[1] = hf ? x67 : P23;
                B.u[2] = hf ? P45 : x01;
                B.u[3] = hf ? P67 : x23;
                const int kc = mt * 2 + kk;
                f16x8 va0 = *(const f16x8*)&VsR[c * 72 + kc * 16 + hf * 8];
                f16x8 va1 = *(const f16x8*)&VsR[(32 + c) * 72 + kc * 16 + hf * 8];
                o[0] = __builtin_amdgcn_mfma_f32_32x32x16_f16(va0, B.v, o[0], 0, 0, 0);
                o[1] = __builtin_amdgcn_mfma_f32_32x32x16_f16(va1, B.v, o[1], 0, 0, 0);
            }
        }

        __syncthreads();   // all waves done reading this tile
        if (jt + 1 < 16) {
            #pragma unroll
            for (int i = 0; i < 4; ++i) {
                int chunk = st + 128 * i;
                int r = chunk >> 3, sg = chunk & 7;
                *(uint4*)&KsW[r * 72 + sg * 8] = kpre[i];
            }
            #pragma unroll
            for (int i = 0; i < 4; ++i) {
                int chunk = st + 128 * i;
                int dp = chunk >> 4, kq = (chunk & 15) * 4;
                uint2 lo, hi;
                lo.x = PERM(vpre[i].y, vpre[i].x, 0x05040100u); hi.x = PERM(vpre[i].y, vpre[i].x, 0x07060302u);
                lo.y = PERM(vpre[i].w, vpre[i].z, 0x05040100u); hi.y = PERM(vpre[i].w, vpre[i].z, 0x07060302u);
                *(uint2*)&VsW[(2 * dp) * 72 + kq]     = lo;
                *(uint2*)&VsW[(2 * dp + 1) * 72 + kq] = hi;
            }
        }
        __syncthreads();   // new tile visible
    }

    // ---- combine key-halves through LDS (plain sums; fixed-max softmax) ----
    float* Red = (float*)SMEM;
    if (kv == 1) {
        float* r = Red + ((size_t)wq * 64 + lane) * 33;
        #pragma unroll
        for (int i = 0; i < 16; ++i) r[i] = o[0][i];
        #pragma unroll
        for (int i = 0; i < 16; ++i) r[16 + i] = o[1][i];
        r[32] = lpart;
    }
    __syncthreads();
    if (kv == 0) {
        const float* r = Red + ((size_t)wq * 64 + lane) * 33;
        #pragma unroll
        for (int i = 0; i < 16; ++i) o[0][i] += r[i];
        #pragma unroll
        for (int i = 0; i < 16; ++i) o[1][i] += r[16 + i];
        lpart += r[32];
        float ltot = lpart + __shfl_xor(lpart, 32);
        float invl = 1.0f / ltot;
        const int b = bh >> 4, h = bh & 15;
        const int pos = qb * 64 + wq * 32 + c;
        float* obase = out + ((size_t)b * NSEQ + pos) * (NH * DH) + h * DH;
        #pragma unroll
        for (int mt = 0; mt < 2; ++mt)
            #pragma unroll
            for (int g = 0; g < 4; ++g) {
                float4 r4 = make_float4(o[mt][g * 4 + 0] * invl, o[mt][g * 4 + 1] * invl,
                                        o[mt][g * 4 + 2] * invl, o[mt][g * 4 + 3] * invl);
                *(float4*)(obase + mt * 32 + g * 8 + hf * 4) = r4;
            }
    }
}

extern "C" void kernel_launch(void* const* d_in, const int* in_sizes, int n_in,
                              void* d_out, int out_size, void* d_ws, size_t ws_size,
                              hipStream_t stream) {
    const float* q  = (const float*)d_in[0];
    const float* k  = (const float*)d_in[1];
    const float* v  = (const float*)d_in[2];
    const float* qs = (const float*)d_in[3];
    const float* ks = (const float*)d_in[4];
    float* outp = (float*)d_out;

    unsigned* qh  = (unsigned*)d_ws;                 // 8 MB
    unsigned* kh  = qh + (size_t)BH * NSEQ * 32;     // 8 MB
    unsigned* vt2 = kh + (size_t)BH * NSEQ * 32;     // 8 MB

    prep_all<<<17408, 256, 0, stream>>>(q, k, v, qs, ks, qh, kh, vt2);
    attn_kernel<<<dim3(NSEQ / 64, BH), 256, 0, stream>>>(qh, kh, vt2, outp);
}

// Round 7
// 152.430 us; speedup vs baseline: 1.2702x; 1.2702x over previous
//
#include <hip/hip_runtime.h>
#include <math.h>

#define BH   32
#define NSEQ 2048
#define DH   64
#define NH   16
#define LOG2E 1.44269504088896f

typedef _Float16 f16x8 __attribute__((ext_vector_type(8)));
typedef __fp16   fp16x2 __attribute__((ext_vector_type(2)));
typedef float    f32x16v __attribute__((ext_vector_type(16)));

#if __has_builtin(__builtin_amdgcn_exp2f)
#define EXP2F(x) __builtin_amdgcn_exp2f(x)
#else
#define EXP2F(x) exp2f(x)
#endif

static __device__ __forceinline__ unsigned pkrtz(float a, float b) {
    fp16x2 r = __builtin_amdgcn_cvt_pkrtz(a, b);
    return __builtin_bit_cast(unsigned, r);
}
static __device__ __forceinline__ unsigned packh_rne(float a, float b) {
    union { _Float16 h[2]; unsigned u; } x;
    x.h[0] = (_Float16)a; x.h[1] = (_Float16)b;
    return x.u;
}
#if __has_builtin(__builtin_amdgcn_perm)
#define PERM(a, b, s) __builtin_amdgcn_perm((a), (b), (s))
#else
static __device__ __forceinline__ unsigned PERM(unsigned a, unsigned b, unsigned s) {
    if (s == 0x05040100u) return (b & 0xffffu) | (a << 16);
    return (b >> 16) | (a & 0xffff0000u);
}
#endif

// cos/sin of pos * 10000^(-p/32) via revolutions + hw transcendentals
static __device__ __forceinline__ float2 rope_cs(int pos, int p) {
    // rev = pos * 10000^(-p/32) / (2*pi)
    float invf_rev = EXP2F(-(float)p * (13.287712379549449f / 32.0f)) * 0.15915494309189535f;
    float rev = (float)pos * invf_rev;
    float fr = rev - floorf(rev);
    float th = fr * 6.283185307179586f;
    return make_float2(__cosf(th), __sinf(th));
}

// ---------------- fused prep: q-norm/rope, k-norm/rope, v-pack ---------------
// grid.x: [0,8192) q blocks (8 rows), [8192,16384) k blocks, [16384,17408) v tiles.
__global__ __launch_bounds__(256) void prep_all(
    const float* __restrict__ q, const float* __restrict__ k, const float* __restrict__ v,
    const float* __restrict__ qs, const float* __restrict__ ksc,
    unsigned* __restrict__ qh, unsigned* __restrict__ kh, unsigned* __restrict__ vt2) {
    const int bid = blockIdx.x;
    const int t = threadIdx.x;
    if (bid < 16384) {
        const bool isq = bid < 8192;
        const float* in = isq ? q : k;
        const float* sc = isq ? qs : ksc;
        unsigned* outp  = isq ? qh : kh;
        const float smul = isq ? 0.125f * LOG2E : 1.0f;
        const int sb = bid & 8191;
        const int w = t >> 6, lane = t & 63;
        const int c = lane & 31, hfr = lane >> 5;
        const int row = sb * 8 + w * 2 + hfr;
        float2 x2 = *(const float2*)(in + (size_t)row * DH + 2 * c);
        float ss = x2.x * x2.x + x2.y * x2.y;
        #pragma unroll
        for (int off = 16; off > 0; off >>= 1) ss += __shfl_xor(ss, off);
        float inv = 1.0f / fmaxf(sqrtf(ss), 1e-12f);
        float2 s2 = *(const float2*)(sc + 2 * c);
        float t0 = x2.x * inv * s2.x;
        float t1 = x2.y * inv * s2.y;
        float p0 = __shfl_xor(t0, 16);
        float p1 = __shfl_xor(t1, 16);
        float r0 = (c < 16) ? -p0 : p0;
        float r1 = (c < 16) ? -p1 : p1;
        int pos = row & (NSEQ - 1);
        int pp = (2 * c) & 31;
        float2 cs0 = rope_cs(pos, pp);
        float2 cs1 = rope_cs(pos, pp + 1);
        float o0 = (t0 * cs0.x + r0 * cs0.y) * smul;
        float o1 = (t1 * cs1.x + r1 * cs1.y) * smul;
        outp[row * 32 + c] = packh_rne(o0, o1);
    } else {
        // V: fp32 [bh][key][dim] -> u32 dim-pairs [bh][dp=32][key] via LDS bounce
        const int sb = bid - 16384;
        const int kt = sb & 31, bh = sb >> 5;
        __shared__ float Lv[64 * 68];
        #pragma unroll
        for (int i = 0; i < 4; ++i) {
            int chunk = t + 256 * i;
            int r = chunk >> 4, fg = chunk & 15;
            *(float4*)&Lv[r * 68 + fg * 4] =
                *(const float4*)(v + ((size_t)bh * NSEQ + kt * 64 + r) * DH + fg * 4);
        }
        __syncthreads();
        const int dp = t >> 3, kg = t & 7;
        unsigned u[8];
        #pragma unroll
        for (int j = 0; j < 8; ++j) {
            int key = kg * 8 + j;
            float2 f2 = *(const float2*)&Lv[key * 68 + 2 * dp];
            u[j] = pkrtz(f2.x, f2.y);
        }
        unsigned* dst = vt2 + ((size_t)bh * 32 + dp) * NSEQ + kt * 64 + kg * 8;
        *(uint4*)(dst + 0) = make_uint4(u[0], u[1], u[2], u[3]);
        *(uint4*)(dst + 4) = make_uint4(u[4], u[5], u[6], u[7]);
    }
}

// ---------------- flash attention: 2-wave WG, 64 q-rows, full-K stream -------
// WG 128 = 2 waves; wave w owns qrows qb*64 + w*32 + c (c = lane&31).
// 64-key tiles, 32 iters, double-buffered LDS (36 KB) + register prefetch.
// Fixed-max softmax (scores bounded by l2norm); P C-layout -> B-frag in-register.
// 1024 WGs -> 4 WGs/CU; launch_bounds(128,2) -> 256-reg cap (no spill).
__global__ __launch_bounds__(128, 2) void attn_kernel(
    const unsigned* __restrict__ qh, const unsigned* __restrict__ khg,
    const unsigned* __restrict__ vt2, float* __restrict__ out) {

    __shared__ _Float16 Ks[2][64 * 72];
    __shared__ _Float16 Vs[2][64 * 72];

    const int bh = blockIdx.y, qb = blockIdx.x;
    const int tid = threadIdx.x;
    const int w = tid >> 6, lane = tid & 63;
    const int c = lane & 31, hf = lane >> 5;

    const _Float16* qbase = (const _Float16*)qh + ((size_t)bh * NSEQ + qb * 64) * DH;
    const _Float16* kbase = (const _Float16*)khg + (size_t)bh * NSEQ * DH;
    const unsigned* vbase = vt2 + (size_t)bh * 32 * NSEQ;

    // stage K/V tile 0 (K: 512 uint4 chunks; V: 512 uint4 chunks of 4 keys)
    #pragma unroll
    for (int i = 0; i < 4; ++i) {
        int chunk = tid + 128 * i;
        int r = chunk >> 3, sg = chunk & 7;
        *(uint4*)&Ks[0][r * 72 + sg * 8] = *(const uint4*)(kbase + r * DH + sg * 8);
    }
    #pragma unroll
    for (int i = 0; i < 4; ++i) {
        int chunk = tid + 128 * i;
        int dp = chunk >> 4, kq = (chunk & 15) * 4;
        uint4 vr = *(const uint4*)(vbase + (size_t)dp * NSEQ + kq);
        uint2 lo, hi;
        lo.x = PERM(vr.y, vr.x, 0x05040100u); hi.x = PERM(vr.y, vr.x, 0x07060302u);
        lo.y = PERM(vr.w, vr.z, 0x05040100u); hi.y = PERM(vr.w, vr.z, 0x07060302u);
        *(uint2*)&Vs[0][(2 * dp) * 72 + kq]     = lo;
        *(uint2*)&Vs[0][(2 * dp + 1) * 72 + kq] = hi;
    }

    // Q frags from global: B[k=dim][n=qrow]
    f16x8 qf[4];
    #pragma unroll
    for (int ks = 0; ks < 4; ++ks)
        qf[ks] = *(const f16x8*)(qbase + (w * 32 + c) * DH + ks * 16 + hf * 8);

    f32x16v o[2];
    #pragma unroll
    for (int mt = 0; mt < 2; ++mt)
        #pragma unroll
        for (int r = 0; r < 16; ++r) o[mt][r] = 0.f;
    float lpart = 0.f;

    __syncthreads();

    for (int jt = 0; jt < 32; ++jt) {
        const int cur = jt & 1;
        uint4 kpre[4], vpre[4];
        if (jt + 1 < 32) {
            #pragma unroll
            for (int i = 0; i < 4; ++i) {
                int chunk = tid + 128 * i;
                int r = chunk >> 3, sg = chunk & 7;
                kpre[i] = *(const uint4*)(kbase + (size_t)(jt + 1) * 64 * DH + r * DH + sg * 8);
            }
            #pragma unroll
            for (int i = 0; i < 4; ++i) {
                int chunk = tid + 128 * i;
                int dp = chunk >> 4, kq = (chunk & 15) * 4;
                vpre[i] = *(const uint4*)(vbase + (size_t)dp * NSEQ + (jt + 1) * 64 + kq);
            }
        }

        // S^T = K * Q^T : s[mt] = keys mt*32.., qrow = c, key = (r&3)+8*(r>>2)+4*hf
        f32x16v s[2];
        #pragma unroll
        for (int mt = 0; mt < 2; ++mt)
            #pragma unroll
            for (int r = 0; r < 16; ++r) s[mt][r] = 0.f;
        #pragma unroll
        for (int ks = 0; ks < 4; ++ks) {
            f16x8 ka0 = *(const f16x8*)&Ks[cur][c * 72 + ks * 16 + hf * 8];
            f16x8 ka1 = *(const f16x8*)&Ks[cur][(32 + c) * 72 + ks * 16 + hf * 8];
            s[0] = __builtin_amdgcn_mfma_f32_32x32x16_f16(ka0, qf[ks], s[0], 0, 0, 0);
            s[1] = __builtin_amdgcn_mfma_f32_32x32x16_f16(ka1, qf[ks], s[1], 0, 0, 0);
        }

        // exp2 (fixed max) + running denominator
        #pragma unroll
        for (int mt = 0; mt < 2; ++mt)
            #pragma unroll
            for (int r = 0; r < 16; ++r) {
                float pv = EXP2F(s[mt][r]);
                s[mt][r] = pv;
                lpart += pv;
            }

        // O^T += V^T * P^T ; B-frags built in-register from C-layout
        #pragma unroll
        for (int mt = 0; mt < 2; ++mt) {
            #pragma unroll
            for (int kk = 0; kk < 2; ++kk) {
                unsigned P01 = pkrtz(s[mt][kk * 8 + 0], s[mt][kk * 8 + 1]);
                unsigned P23 = pkrtz(s[mt][kk * 8 + 2], s[mt][kk * 8 + 3]);
                unsigned P45 = pkrtz(s[mt][kk * 8 + 4], s[mt][kk * 8 + 5]);
                unsigned P67 = pkrtz(s[mt][kk * 8 + 6], s[mt][kk * 8 + 7]);
                unsigned x01 = (unsigned)__shfl_xor((int)P01, 32);
                unsigned x23 = (unsigned)__shfl_xor((int)P23, 32);
                unsigned x45 = (unsigned)__shfl_xor((int)P45, 32);
                unsigned x67 = (unsigned)__shfl_xor((int)P67, 32);
                union { unsigned u[4]; f16x8 v; } B;
                B.u[0] = hf ? x45 : P01;
                B.u[1] = hf ? x67 : P23;
                B.u[2] = hf ? P45 : x01;
                B.u[3] = hf ? P67 : x23;
                const int kc = mt * 2 + kk;
                f16x8 va0 = *(const f16x8*)&Vs[cur][c * 72 + kc * 16 + hf * 8];
                f16x8 va1 = *(const f16x8*)&Vs[cur][(32 + c) * 72 + kc * 16 + hf * 8];
                o[0] = __builtin_amdgcn_mfma_f32_32x32x16_f16(va0, B.v, o[0], 0, 0, 0);
                o[1] = __builtin_amdgcn_mfma_f32_32x32x16_f16(va1, B.v, o[1], 0, 0, 0);
            }
        }

        // commit prefetch to other buffer
        if (jt + 1 < 32) {
            #pragma unroll
            for (int i = 0; i < 4; ++i) {
                int chunk = tid + 128 * i;
                int r = chunk >> 3, sg = chunk & 7;
                *(uint4*)&Ks[1 - cur][r * 72 + sg * 8] = kpre[i];
            }
            #pragma unroll
            for (int i = 0; i < 4; ++i) {
                int chunk = tid + 128 * i;
                int dp = chunk >> 4, kq = (chunk & 15) * 4;
                uint2 lo, hi;
                lo.x = PERM(vpre[i].y, vpre[i].x, 0x05040100u); hi.x = PERM(vpre[i].y, vpre[i].x, 0x07060302u);
                lo.y = PERM(vpre[i].w, vpre[i].z, 0x05040100u); hi.y = PERM(vpre[i].w, vpre[i].z, 0x07060302u);
                *(uint2*)&Vs[1 - cur][(2 * dp) * 72 + kq]     = lo;
                *(uint2*)&Vs[1 - cur][(2 * dp + 1) * 72 + kq] = hi;
            }
        }
        __syncthreads();
    }

    // epilogue: dim = mt*32 + g*8 + hf*4 + (r&3)
    float ltot = lpart + __shfl_xor(lpart, 32);
    float invl = 1.0f / ltot;
    const int b = bh >> 4, h = bh & 15;
    const int pos = qb * 64 + w * 32 + c;
    float* obase = out + ((size_t)b * NSEQ + pos) * (NH * DH) + h * DH;
    #pragma unroll
    for (int mt = 0; mt < 2; ++mt)
        #pragma unroll
        for (int g = 0; g < 4; ++g) {
            float4 r4 = make_float4(o[mt][g * 4 + 0] * invl, o[mt][g * 4 + 1] * invl,
                                    o[mt][g * 4 + 2] * invl, o[mt][g * 4 + 3] * invl);
            *(float4*)(obase + mt * 32 + g * 8 + hf * 4) = r4;
        }
}

extern "C" void kernel_launch(void* const* d_in, const int* in_sizes, int n_in,
                              void* d_out, int out_size, void* d_ws, size_t ws_size,
                              hipStream_t stream) {
    const float* q  = (const float*)d_in[0];
    const float* k  = (const float*)d_in[1];
    const float* v  = (const float*)d_in[2];
    const float* qs = (const float*)d_in[3];
    const float* ks = (const float*)d_in[4];
    float* outp = (float*)d_out;

    unsigned* qh  = (unsigned*)d_ws;                 // 8 MB
    unsigned* kh  = qh + (size_t)BH * NSEQ * 32;     // 8 MB
    unsigned* vt2 = kh + (size_t)BH * NSEQ * 32;     // 8 MB

    prep_all<<<17408, 256, 0, stream>>>(q, k, v, qs, ks, qh, kh, vt2);
    attn_kernel<<<dim3(NSEQ / 64, BH), 128, 0, stream>>>(qh, kh, vt2, outp);
}